// Round 4
// baseline (4630.180 us; speedup 1.0000x reference)
//
#include <hip/hip_runtime.h>
#include <hip/hip_bf16.h>
#include <hip/hip_cooperative_groups.h>
#include <stdint.h>

namespace cg = cooperative_groups;

// Problem dims
#define SEQ   256
#define BATCH 128
#define INPD  256
#define HID   512
#define OUTD  512
#define G4    2048   // 4*HID

typedef __attribute__((ext_vector_type(8))) short short8;
typedef __attribute__((ext_vector_type(4))) float f32x4;

typedef __attribute__((address_space(1))) void gv_t;
typedef __attribute__((address_space(3))) void lv_t;

__device__ inline unsigned short f2b(float f) {
  union { float f; uint32_t u; } v; v.f = f;
  uint32_t r = v.u + 0x7fffu + ((v.u >> 16) & 1u);   // RNE
  return (unsigned short)(r >> 16);
}
__device__ inline float b2f(unsigned short b) {
  union { uint32_t u; float f; } v; v.u = ((uint32_t)b) << 16; return v.f;
}
__device__ inline float fsig(float x) { return 1.f / (1.f + __expf(-x)); }
__device__ inline float ftanh(float x) {
  float a = fabsf(x);
  float u = __expf(-2.f * a);
  float t = (1.f - u) / (1.f + u);
  return copysignf(t, x);
}
__device__ inline f32x4 mfma16(short8 a, short8 b, f32x4 c) {
  return __builtin_amdgcn_mfma_f32_16x16x32_bf16(a, b, c, 0, 0, 0);
}
__device__ inline void llds16(const void* g, void* l) {
  __builtin_amdgcn_global_load_lds((gv_t*)g, (lv_t*)l, 16, 0, 0);
}

// ---------------- prep kernels ----------------

__global__ __launch_bounds__(256) void k_cast_bf16(const float* __restrict__ in,
                                                   unsigned short* __restrict__ out, int n4) {
  int i = blockIdx.x * 256 + threadIdx.x;
  if (i >= n4) return;
  float4 v = ((const float4*)in)[i];
  ushort4 o;
  o.x = f2b(v.x); o.y = f2b(v.y); o.z = f2b(v.z); o.w = f2b(v.w);
  ((ushort4*)out)[i] = o;
}

// out[n][k] = (bf16) in[k][n]   (in: [K][N] fp32)
__global__ __launch_bounds__(256) void k_transpose_cast(const float* __restrict__ in,
                                                        unsigned short* __restrict__ out,
                                                        int K, int N) {
  __shared__ float tile[32][33];
  int n0 = blockIdx.x * 32, k0 = blockIdx.y * 32;
  int tx = threadIdx.x & 31, ty = threadIdx.x >> 5;   // ty 0..7
  for (int r = ty; r < 32; r += 8) tile[r][tx] = in[(size_t)(k0 + r) * N + n0 + tx];
  __syncthreads();
  for (int r = ty; r < 32; r += 8) out[(size_t)(n0 + r) * K + k0 + tx] = f2b(tile[tx][r]);
}

__global__ __launch_bounds__(256) void k_zero(uint32_t* __restrict__ p, int n) {
  int i = blockIdx.x * 256 + threadIdx.x;
  if (i < n) p[i] = 0;
}

__global__ void k_diag(float* __restrict__ out, float v) {
  if (threadIdx.x == 0 && blockIdx.x == 0) out[0] = v;
}

// ---------------- bf16 GEMM:  C[m][n] = A[m][:]·Bt[n][:] + bias[n] ----------------
// A: [M][K] bf16 row-major, Bt: [N][K] bf16 (B transposed). 128x128 tile, BK=64,
// 4 waves of 64x64, double-buffered LDS, global_load_lds w/ pre-swizzled source (rule 21).
template<bool F32OUT>
__global__ __launch_bounds__(256) void k_gemm(
    const unsigned short* __restrict__ A,
    const unsigned short* __restrict__ Bt0, const unsigned short* __restrict__ Bt1,
    const float* __restrict__ bias0, const float* __restrict__ bias1,
    void* __restrict__ C0, void* __restrict__ C1,
    int ldc, int K, int ntilesPerDir)
{
  __shared__ unsigned short lds[2][2][8192];   // [buf][A/B][128 rows * 64 k] = 64 KB
  int bx = blockIdx.x;
  int dir = bx / ntilesPerDir;
  int ntile = bx - dir * ntilesPerDir;
  int mtile = blockIdx.y;
  const unsigned short* Bt = dir ? Bt1 : Bt0;
  const float* bias = dir ? bias1 : bias0;
  int m0 = mtile * 128, n0 = ntile * 128;
  int tid = threadIdx.x;
  int wave = tid >> 6, lane = tid & 63;
  int wr = wave >> 1, wc = wave & 1;
  int nkt = K >> 6;

  auto stage = [&](int buf, int kt) {
    #pragma unroll
    for (int half = 0; half < 2; half++) {
      const unsigned short* src = half ? Bt : A;
      int rowbase = half ? n0 : m0;
      #pragma unroll
      for (int i = 0; i < 4; i++) {
        int o = (i * 4 + wave) * 1024 + lane * 16;       // byte offset in 16KB tile
        int row = o >> 7;
        int kb  = o & 127;
        int kbs = kb ^ ((row & 7) << 4);                 // inverse-swizzled global source
        const char* ga = (const char*)src + (((size_t)(rowbase + row) * K + kt * 64) << 1) + kbs;
        char* lb = (char*)(&lds[buf][half][0]) + (i * 4 + wave) * 1024;  // wave-uniform base
        llds16(ga, lb);
      }
    }
  };

  f32x4 acc[4][4];
  #pragma unroll
  for (int i = 0; i < 4; i++)
    #pragma unroll
    for (int j = 0; j < 4; j++) { f32x4 z = {0.f,0.f,0.f,0.f}; acc[i][j] = z; }

  stage(0, 0);
  __syncthreads();
  for (int kt = 0; kt < nkt; kt++) {
    int buf = kt & 1;
    if (kt + 1 < nkt) stage(buf ^ 1, kt + 1);
    #pragma unroll
    for (int ks = 0; ks < 2; ks++) {
      short8 a[4], b[4];
      int kb = ks * 64 + ((lane >> 4) << 4);
      #pragma unroll
      for (int rt = 0; rt < 4; rt++) {
        int row = wr * 64 + rt * 16 + (lane & 15);
        int addr = row * 128 + (kb ^ ((row & 7) << 4));
        a[rt] = *(const short8*)((const char*)&lds[buf][0][0] + addr);
      }
      #pragma unroll
      for (int ct = 0; ct < 4; ct++) {
        int row = wc * 64 + ct * 16 + (lane & 15);
        int addr = row * 128 + (kb ^ ((row & 7) << 4));
        b[ct] = *(const short8*)((const char*)&lds[buf][1][0] + addr);
      }
      #pragma unroll
      for (int rt = 0; rt < 4; rt++)
        #pragma unroll
        for (int ct = 0; ct < 4; ct++)
          acc[rt][ct] = mfma16(a[rt], b[ct], acc[rt][ct]);
    }
    __syncthreads();
  }

  char* C = (char*)(dir ? C1 : C0);
  #pragma unroll
  for (int rt = 0; rt < 4; rt++) {
    #pragma unroll
    for (int ct = 0; ct < 4; ct++) {
      int coll = wc * 64 + ct * 16 + (lane & 15);
      float bv = bias[n0 + coll];
      #pragma unroll
      for (int r = 0; r < 4; r++) {
        int rowl = wr * 64 + rt * 16 + ((lane >> 4) << 2) + r;
        size_t off = (size_t)(m0 + rowl) * ldc + (n0 + coll);
        float v = acc[rt][ct][r] + bv;
        if (F32OUT) ((float*)C)[off] = v;
        else        ((unsigned short*)C)[off] = f2b(v);
      }
    }
  }
}

// ---------------- persistent bidirectional LSTM recurrence (cooperative) ----------------
// 64 WGs x 256 thr, grid-synced via cg. WG (dir, cc) owns h-cols [16cc,16cc+16)
// => 64 gate-cols. Fused x-projection: preact = [h_{t-1} | x_t] @ [wh; wx] (K=768),
// weight slice resident in LDS (bf16, XOR-swizzled, 96KB dynamic). MFMA C/D layout
// puts all 4 gate preacts of a cell in one lane -> in-register gate update, c in regs.
__global__ __launch_bounds__(256, 1) void k_lstm(
    const float* __restrict__ whf, const float* __restrict__ whb,
    const float* __restrict__ wxf, const float* __restrict__ wxb,
    const float* __restrict__ bhf, const float* __restrict__ bhb,
    const float* __restrict__ bxf, const float* __restrict__ bxb,
    const unsigned short* __restrict__ xbf,  // [256*128][256] bf16
    unsigned short* __restrict__ hbuf,       // [2][2][128][512] bf16 (zeroed)
    unsigned short* __restrict__ hs,         // [256][128][1024] bf16
    float* __restrict__ dout)
{
  extern __shared__ char smem[];             // 96KB: [lg 0..63][k 0..767] bf16 swizzled
  cg::grid_group grid = cg::this_grid();

  int wg = blockIdx.x;
  int dir = wg >> 5;
  int cc = wg & 31;
  int hcol0 = cc << 4;
  const float* wh = dir ? whb : whf;
  const float* wx = dir ? wxb : wxf;
  const float* bh = dir ? bhb : bhf;
  const float* bx = dir ? bxb : bxf;
  int tid = threadIdx.x;
  int lane = tid & 63;
  int wave = tid >> 6;
  int jloc = lane & 15;
  int qq = lane >> 4;

  // stage [wh; wx] slice: lg -> gate (lg>>4), col hcol0+(lg&15); k<512: wh, k>=512: wx
  for (int i = tid; i < 64 * 768; i += 256) {
    int lg = i & 63, k = i >> 6;
    int gcol = ((lg >> 4) << 9) + hcol0 + (lg & 15);
    float v = (k < 512) ? wh[(size_t)k * G4 + gcol]
                        : wx[(size_t)(k - 512) * G4 + gcol];
    int byteoff = lg * 1536 + ((k << 1) ^ ((lg & 7) << 4));
    *(unsigned short*)(smem + byteoff) = f2b(v);
  }
  float bh_r[4];
  #pragma unroll
  for (int g = 0; g < 4; g++)
    bh_r[g] = bh[(g << 9) + hcol0 + jloc] + bx[(g << 9) + hcol0 + jloc];
  float cr[8];
  #pragma unroll
  for (int r = 0; r < 8; r++) cr[r] = 0.f;
  __syncthreads();

  for (int s = 0; s < 256; s++) {
    int t = dir ? (255 - s) : s;
    const unsigned short* hprev = hbuf + ((size_t)(dir * 2 + (s & 1))) * (128 * 512);
    const unsigned short* xt = xbf + (size_t)t * (128 * 256);

    // acc[rt][ct][r] => preact(row = 32*wave+16*rt+4*qq+r, gate ct, col hcol0+jloc)
    f32x4 acc[2][4];
    #pragma unroll
    for (int i = 0; i < 2; i++)
      #pragma unroll
      for (int j = 0; j < 4; j++) { f32x4 z = {0.f,0.f,0.f,0.f}; acc[i][j] = z; }

    // h part: k 0..511
    #pragma unroll 4
    for (int ks = 0; ks < 16; ks++) {
      int kidx = ks * 32 + qq * 8;
      short8 b[4];
      #pragma unroll
      for (int ct = 0; ct < 4; ct++) {
        int lg = ct * 16 + jloc;
        b[ct] = *(const short8*)(smem + lg * 1536 + ((kidx << 1) ^ ((lg & 7) << 4)));
      }
      #pragma unroll
      for (int rt = 0; rt < 2; rt++) {
        int row = wave * 32 + rt * 16 + jloc;
        short8 a = *(const short8*)(hprev + (size_t)row * 512 + kidx);
        #pragma unroll
        for (int ct = 0; ct < 4; ct++)
          acc[rt][ct] = mfma16(a, b[ct], acc[rt][ct]);
      }
    }
    // x part: k 512..767  (A from xbf[t])
    #pragma unroll 4
    for (int ks = 16; ks < 24; ks++) {
      int kidx = ks * 32 + qq * 8;
      short8 b[4];
      #pragma unroll
      for (int ct = 0; ct < 4; ct++) {
        int lg = ct * 16 + jloc;
        b[ct] = *(const short8*)(smem + lg * 1536 + ((kidx << 1) ^ ((lg & 7) << 4)));
      }
      #pragma unroll
      for (int rt = 0; rt < 2; rt++) {
        int row = wave * 32 + rt * 16 + jloc;
        short8 a = *(const short8*)(xt + (size_t)row * 256 + (kidx - 512));
        #pragma unroll
        for (int ct = 0; ct < 4; ct++)
          acc[rt][ct] = mfma16(a, b[ct], acc[rt][ct]);
      }
    }

    // ---- in-register gate update ----
    unsigned short* hnew = hbuf + ((size_t)(dir * 2 + ((s + 1) & 1))) * (128 * 512);
    unsigned short* hst = hs + (size_t)t * (128 * 1024) + (dir << 9);
    #pragma unroll
    for (int rt = 0; rt < 2; rt++) {
      #pragma unroll
      for (int r = 0; r < 4; r++) {
        int row = wave * 32 + rt * 16 + qq * 4 + r;
        int ci = rt * 4 + r;
        float gi = acc[rt][0][r] + bh_r[0];
        float gf = acc[rt][1][r] + bh_r[1];
        float go = acc[rt][2][r] + bh_r[2];
        float gc = acc[rt][3][r] + bh_r[3];
        float I = fsig(gi), F = fsig(gf), O = fsig(go), Ct = ftanh(gc);
        float cn = F * cr[ci] + I * Ct;
        cr[ci] = cn;
        float h = O * ftanh(cn);
        unsigned short hb = f2b(h);
        hnew[(size_t)row * 512 + hcol0 + jloc] = hb;
        hst[(size_t)row * 1024 + hcol0 + jloc] = hb;
        if (s == 255) {
          size_t base = (size_t)SEQ * BATCH * OUTD + (size_t)dir * (BATCH * HID)
                      + (size_t)row * HID + hcol0 + jloc;
          dout[base] = h;                            // hN
          dout[base + 2 * (BATCH * HID)] = cn;       // cN
        }
      }
    }

    grid.sync();
  }
}

// ---------------- launcher ----------------
extern "C" void kernel_launch(void* const* d_in, const int* in_sizes, int n_in,
                              void* d_out, int out_size, void* d_ws, size_t ws_size,
                              hipStream_t stream)
{
  const float* x      = (const float*)d_in[0];
  const float* wx_fwd = (const float*)d_in[1];
  const float* bx_fwd = (const float*)d_in[2];
  const float* wh_fwd = (const float*)d_in[3];
  const float* bh_fwd = (const float*)d_in[4];
  const float* wx_bwd = (const float*)d_in[5];
  const float* bx_bwd = (const float*)d_in[6];
  const float* wh_bwd = (const float*)d_in[7];
  const float* bh_bwd = (const float*)d_in[8];
  const float* wfc    = (const float*)d_in[9];
  const float* bfc    = (const float*)d_in[10];
  float* out = (float*)d_out;

  // ws layout (bytes); total ~85.5 MB (ws_size observed ~260 MB)
  const size_t WS_NEED = 85458944ULL;
  char* ws = (char*)d_ws;
  unsigned short* xbf  = (unsigned short*)(ws + 0);           // 16 MB  [32768][256] bf16
  unsigned short* wfcT = (unsigned short*)(ws + 16777216);    // 1 MB   [512][1024] bf16
  unsigned short* hs   = (unsigned short*)(ws + 17825792);    // 64 MB  [256][128][1024] bf16
  unsigned short* hbuf = (unsigned short*)(ws + 84934656);    // 512 KB [2][2][128][512] bf16

  (void)in_sizes; (void)n_in; (void)out_size;

  if (ws_size < WS_NEED) {
    // clean diagnostic failure instead of OOB crash: absmax ~= ws MB
    k_diag<<<1, 64, 0, stream>>>(out, (float)(ws_size >> 20));
    return;
  }

  hipFuncSetAttribute((const void*)k_lstm, hipFuncAttributeMaxDynamicSharedMemorySize, 98304);

  // prep
  k_cast_bf16<<<8192, 256, 0, stream>>>(x, xbf, 2097152);
  k_transpose_cast<<<dim3(16, 32), 256, 0, stream>>>(wfc, wfcT, 1024, 512);
  k_zero<<<512, 256, 0, stream>>>((uint32_t*)hbuf, 131072);

  // recurrence (cooperative: grid-wide sync each step), x-projection fused
  {
    const float* a0 = wh_fwd; const float* a1 = wh_bwd;
    const float* a2 = wx_fwd; const float* a3 = wx_bwd;
    const float* a4 = bh_fwd; const float* a5 = bh_bwd;
    const float* a6 = bx_fwd; const float* a7 = bx_bwd;
    const unsigned short* a8 = xbf;
    unsigned short* a9 = hbuf;
    unsigned short* a10 = hs;
    float* a11 = out;
    void* args[] = {(void*)&a0, (void*)&a1, (void*)&a2, (void*)&a3,
                    (void*)&a4, (void*)&a5, (void*)&a6, (void*)&a7,
                    (void*)&a8, (void*)&a9, (void*)&a10, (void*)&a11};
    hipLaunchCooperativeKernel((const void*)k_lstm, dim3(64), dim3(256), args, 98304, stream);
  }

  // outputs = [hs_f | hs_b] @ wfc + bfc  (fp32 out)
  k_gemm<true><<<dim3(4, 256), 256, 0, stream>>>(
      hs, wfcT, wfcT, bfc, bfc, (void*)out, (void*)out, OUTD, 2 * HID, 4);
}

// Round 6
// 3256.982 us; speedup vs baseline: 1.4216x; 1.4216x over previous
//
#include <hip/hip_runtime.h>
#include <hip/hip_bf16.h>
#include <stdint.h>

// Problem dims
#define SEQ   256
#define BATCH 128
#define INPD  256
#define HID   512
#define OUTD  512
#define G4    2048   // 4*HID

typedef __attribute__((ext_vector_type(8))) short short8;
typedef __attribute__((ext_vector_type(4))) float f32x4;

typedef __attribute__((address_space(1))) void gv_t;
typedef __attribute__((address_space(3))) void lv_t;

__device__ inline unsigned short f2b(float f) {
  union { float f; uint32_t u; } v; v.f = f;
  uint32_t r = v.u + 0x7fffu + ((v.u >> 16) & 1u);   // RNE
  return (unsigned short)(r >> 16);
}
__device__ inline float b2f(unsigned short b) {
  union { uint32_t u; float f; } v; v.u = ((uint32_t)b) << 16; return v.f;
}
__device__ inline float fsig(float x) { return 1.f / (1.f + __expf(-x)); }
__device__ inline float ftanh(float x) {
  float a = fabsf(x);
  float u = __expf(-2.f * a);
  float t = (1.f - u) / (1.f + u);
  return copysignf(t, x);
}
__device__ inline f32x4 mfma16(short8 a, short8 b, f32x4 c) {
  return __builtin_amdgcn_mfma_f32_16x16x32_bf16(a, b, c, 0, 0, 0);
}
__device__ inline void llds16(const void* g, void* l) {
  __builtin_amdgcn_global_load_lds((gv_t*)g, (lv_t*)l, 16, 0, 0);
}
// device-scope (sc1) coherent h exchange: compiler schedules waitcnts
__device__ inline short8 ld_h_dev(const unsigned long long* h2row, int g) {
  union { unsigned long long q[2]; short8 v; } u;
  u.q[0] = __hip_atomic_load(h2row + g,     __ATOMIC_RELAXED, __HIP_MEMORY_SCOPE_AGENT);
  u.q[1] = __hip_atomic_load(h2row + g + 1, __ATOMIC_RELAXED, __HIP_MEMORY_SCOPE_AGENT);
  return u.v;
}

// ---------------- prep kernels ----------------

__global__ __launch_bounds__(256) void k_cast_bf16(const float* __restrict__ in,
                                                   unsigned short* __restrict__ out, int n4) {
  int i = blockIdx.x * 256 + threadIdx.x;
  if (i >= n4) return;
  float4 v = ((const float4*)in)[i];
  ushort4 o;
  o.x = f2b(v.x); o.y = f2b(v.y); o.z = f2b(v.z); o.w = f2b(v.w);
  ((ushort4*)out)[i] = o;
}

// out[n][k] = (bf16) in[k][n]   (in: [K][N] fp32)
__global__ __launch_bounds__(256) void k_transpose_cast(const float* __restrict__ in,
                                                        unsigned short* __restrict__ out,
                                                        int K, int N) {
  __shared__ float tile[32][33];
  int n0 = blockIdx.x * 32, k0 = blockIdx.y * 32;
  int tx = threadIdx.x & 31, ty = threadIdx.x >> 5;   // ty 0..7
  for (int r = ty; r < 32; r += 8) tile[r][tx] = in[(size_t)(k0 + r) * N + n0 + tx];
  __syncthreads();
  for (int r = ty; r < 32; r += 8) out[(size_t)(n0 + r) * K + k0 + tx] = f2b(tile[tx][r]);
}

__global__ __launch_bounds__(256) void k_zero(uint32_t* __restrict__ p, int n) {
  int i = blockIdx.x * 256 + threadIdx.x;
  if (i < n) p[i] = 0;
}

__global__ void k_diag(float* __restrict__ out, float v) {
  if (threadIdx.x == 0 && blockIdx.x == 0) out[0] = v;
}

// ---------------- bf16 GEMM:  C[m][n] = A[m][:]·Bt[n][:] + bias[n] ----------------
template<bool F32OUT>
__global__ __launch_bounds__(256) void k_gemm(
    const unsigned short* __restrict__ A,
    const unsigned short* __restrict__ Bt0, const unsigned short* __restrict__ Bt1,
    const float* __restrict__ bias0, const float* __restrict__ bias1,
    void* __restrict__ C0, void* __restrict__ C1,
    int ldc, int K, int ntilesPerDir)
{
  __shared__ unsigned short lds[2][2][8192];   // [buf][A/B][128 rows * 64 k] = 64 KB
  int bx = blockIdx.x;
  int dir = bx / ntilesPerDir;
  int ntile = bx - dir * ntilesPerDir;
  int mtile = blockIdx.y;
  const unsigned short* Bt = dir ? Bt1 : Bt0;
  const float* bias = dir ? bias1 : bias0;
  int m0 = mtile * 128, n0 = ntile * 128;
  int tid = threadIdx.x;
  int wave = tid >> 6, lane = tid & 63;
  int wr = wave >> 1, wc = wave & 1;
  int nkt = K >> 6;

  auto stage = [&](int buf, int kt) {
    #pragma unroll
    for (int half = 0; half < 2; half++) {
      const unsigned short* src = half ? Bt : A;
      int rowbase = half ? n0 : m0;
      #pragma unroll
      for (int i = 0; i < 4; i++) {
        int o = (i * 4 + wave) * 1024 + lane * 16;       // byte offset in 16KB tile
        int row = o >> 7;
        int kb  = o & 127;
        int kbs = kb ^ ((row & 7) << 4);                 // inverse-swizzled global source
        const char* ga = (const char*)src + (((size_t)(rowbase + row) * K + kt * 64) << 1) + kbs;
        char* lb = (char*)(&lds[buf][half][0]) + (i * 4 + wave) * 1024;  // wave-uniform base
        llds16(ga, lb);
      }
    }
  };

  f32x4 acc[4][4];
  #pragma unroll
  for (int i = 0; i < 4; i++)
    #pragma unroll
    for (int j = 0; j < 4; j++) { f32x4 z = {0.f,0.f,0.f,0.f}; acc[i][j] = z; }

  stage(0, 0);
  __syncthreads();
  for (int kt = 0; kt < nkt; kt++) {
    int buf = kt & 1;
    if (kt + 1 < nkt) stage(buf ^ 1, kt + 1);
    #pragma unroll
    for (int ks = 0; ks < 2; ks++) {
      short8 a[4], b[4];
      int kb = ks * 64 + ((lane >> 4) << 4);
      #pragma unroll
      for (int rt = 0; rt < 4; rt++) {
        int row = wr * 64 + rt * 16 + (lane & 15);
        int addr = row * 128 + (kb ^ ((row & 7) << 4));
        a[rt] = *(const short8*)((const char*)&lds[buf][0][0] + addr);
      }
      #pragma unroll
      for (int ct = 0; ct < 4; ct++) {
        int row = wc * 64 + ct * 16 + (lane & 15);
        int addr = row * 128 + (kb ^ ((row & 7) << 4));
        b[ct] = *(const short8*)((const char*)&lds[buf][1][0] + addr);
      }
      #pragma unroll
      for (int rt = 0; rt < 4; rt++)
        #pragma unroll
        for (int ct = 0; ct < 4; ct++)
          acc[rt][ct] = mfma16(a[rt], b[ct], acc[rt][ct]);
    }
    __syncthreads();
  }

  char* C = (char*)(dir ? C1 : C0);
  #pragma unroll
  for (int rt = 0; rt < 4; rt++) {
    #pragma unroll
    for (int ct = 0; ct < 4; ct++) {
      int coll = wc * 64 + ct * 16 + (lane & 15);
      float bv = bias[n0 + coll];
      #pragma unroll
      for (int r = 0; r < 4; r++) {
        int rowl = wr * 64 + rt * 16 + ((lane >> 4) << 2) + r;
        size_t off = (size_t)(m0 + rowl) * ldc + (n0 + coll);
        float v = acc[rt][ct][r] + bv;
        if (F32OUT) ((float*)C)[off] = v;
        else        ((unsigned short*)C)[off] = f2b(v);
      }
    }
  }
}

// ---------------- persistent bidirectional LSTM recurrence ----------------
// 64 WGs x 256 thr. WG (dir, cc) owns h-cols [16cc,16cc+16) => 64 gate-cols;
// [wh; wx] slice (K=768) LDS-resident (bf16, XOR-swizzled, 96KB dynamic).
// Cross-WG h exchange: DEVICE-SCOPE (sc1) relaxed atomics — u64-packed stores
// (4 cols via two shfl_xor) and u64-pair loads. These bypass the non-coherent
// per-XCD L2s (round-5 lesson: `nt` is a hint, NOT a coherence bypass).
// Flags: per-direction relaxed agent-scope monotonic counter; __syncthreads()
// before the flag-add drains vmcnt (sc1 acks = coherence point reached).
__global__ __launch_bounds__(256, 1) void k_lstm(
    const float* __restrict__ whf, const float* __restrict__ whb,
    const float* __restrict__ wxf, const float* __restrict__ wxb,
    const float* __restrict__ bhf, const float* __restrict__ bhb,
    const float* __restrict__ bxf, const float* __restrict__ bxb,
    const unsigned short* __restrict__ xbf,  // [256*128][256] bf16
    unsigned short* __restrict__ hbuf,       // [2][2][128][512] bf16 (zeroed)
    unsigned short* __restrict__ hs,         // [256][128][1024] bf16
    float* __restrict__ dout,
    uint32_t* __restrict__ ctr)              // [2*64] zeroed; ctr[dir*64]
{
  extern __shared__ char smem[];             // 96KB: [lg 0..63][k 0..767] bf16 swizzled
  int wg = blockIdx.x;
  int dir = wg >> 5;
  int cc = wg & 31;
  int hcol0 = cc << 4;
  const float* wh = dir ? whb : whf;
  const float* wx = dir ? wxb : wxf;
  const float* bh = dir ? bhb : bhf;
  const float* bx = dir ? bxb : bxf;
  int tid = threadIdx.x;
  int lane = tid & 63;
  int wave = tid >> 6;
  int jloc = lane & 15;
  int qq = lane >> 4;
  uint32_t* myctr = ctr + dir * 64;

  // stage [wh; wx] slice: lg -> gate (lg>>4), col hcol0+(lg&15); k<512: wh else wx
  for (int i = tid; i < 64 * 768; i += 256) {
    int lg = i & 63, k = i >> 6;
    int gcol = ((lg >> 4) << 9) + hcol0 + (lg & 15);
    float v = (k < 512) ? wh[(size_t)k * G4 + gcol]
                        : wx[(size_t)(k - 512) * G4 + gcol];
    int byteoff = lg * 1536 + ((k << 1) ^ ((lg & 7) << 4));
    *(unsigned short*)(smem + byteoff) = f2b(v);
  }
  float bh_r[4];
  #pragma unroll
  for (int g = 0; g < 4; g++)
    bh_r[g] = bh[(g << 9) + hcol0 + jloc] + bx[(g << 9) + hcol0 + jloc];
  float cr[8];
  #pragma unroll
  for (int r = 0; r < 8; r++) cr[r] = 0.f;
  __syncthreads();

  // acc[rt][ct][r] => preact(row = 32*wave+16*rt+4*qq+r, gate ct, col hcol0+jloc)
  f32x4 acc[2][4];
  #pragma unroll
  for (int i = 0; i < 2; i++)
    #pragma unroll
    for (int j = 0; j < 4; j++) { f32x4 z = {0.f,0.f,0.f,0.f}; acc[i][j] = z; }

  auto xpart = [&](int sn) {   // accumulate x_t @ wx into acc (k 512..767)
    int tn = dir ? (255 - sn) : sn;
    const unsigned short* xt = xbf + (size_t)tn * (128 * 256);
    #pragma unroll 2
    for (int ks = 16; ks < 24; ks++) {
      int kidx = ks * 32 + qq * 8;
      short8 b[4];
      #pragma unroll
      for (int ct = 0; ct < 4; ct++) {
        int lg = ct * 16 + jloc;
        b[ct] = *(const short8*)(smem + lg * 1536 + ((kidx << 1) ^ ((lg & 7) << 4)));
      }
      #pragma unroll
      for (int rt = 0; rt < 2; rt++) {
        int row = wave * 32 + rt * 16 + jloc;
        short8 a = *(const short8*)(xt + (size_t)row * 256 + (kidx - 512));
        #pragma unroll
        for (int ct = 0; ct < 4; ct++)
          acc[rt][ct] = mfma16(a, b[ct], acc[rt][ct]);
      }
    }
  };

  xpart(0);   // overlap-free prologue

  for (int s = 0; s < 256; s++) {
    int t = dir ? (255 - s) : s;

    // ---- wait for h_s (all 32 WGs of this dir finished step s-1) ----
    if (s > 0 && tid == 0) {
      uint32_t target = 32u * (uint32_t)s;
      while (__hip_atomic_load(myctr, __ATOMIC_RELAXED, __HIP_MEMORY_SCOPE_AGENT) < target)
        __builtin_amdgcn_s_sleep(2);
    }
    __syncthreads();

    // ---- h-part MFMA (k 0..511), device-scope coherent h loads ----
    const unsigned long long* h2p = (const unsigned long long*)
        (hbuf + ((size_t)(dir * 2 + (s & 1))) * (128 * 512));
    #pragma unroll 4
    for (int ks = 0; ks < 16; ks++) {
      int kidx = ks * 32 + qq * 8;
      short8 b[4];
      #pragma unroll
      for (int ct = 0; ct < 4; ct++) {
        int lg = ct * 16 + jloc;
        b[ct] = *(const short8*)(smem + lg * 1536 + ((kidx << 1) ^ ((lg & 7) << 4)));
      }
      #pragma unroll
      for (int rt = 0; rt < 2; rt++) {
        int row = wave * 32 + rt * 16 + jloc;
        short8 a = ld_h_dev(h2p + (size_t)row * 128, kidx >> 2);
        #pragma unroll
        for (int ct = 0; ct < 4; ct++)
          acc[rt][ct] = mfma16(a, b[ct], acc[rt][ct]);
      }
    }

    // ---- in-register gate update; pack 4 cols -> u64 sc1 stores ----
    unsigned long long* h2n = (unsigned long long*)
        (hbuf + ((size_t)(dir * 2 + ((s + 1) & 1))) * (128 * 512));
    float hv[2][4], cv[2][4];
    unsigned short hbv[2][4];
    #pragma unroll
    for (int rt = 0; rt < 2; rt++) {
      #pragma unroll
      for (int r = 0; r < 4; r++) {
        int ci = rt * 4 + r;
        float gi = acc[rt][0][r] + bh_r[0];
        float gf = acc[rt][1][r] + bh_r[1];
        float go = acc[rt][2][r] + bh_r[2];
        float gc = acc[rt][3][r] + bh_r[3];
        float I = fsig(gi), F = fsig(gf), O = fsig(go), Ct = ftanh(gc);
        float cn = F * cr[ci] + I * Ct;
        cr[ci] = cn;
        float h = O * ftanh(cn);
        hv[rt][r] = h; cv[rt][r] = cn;
        hbv[rt][r] = f2b(h);
        // lane-quad pack: cols (hcol0 + (jloc&~3)) + 0..3 into one u64
        unsigned int my16 = (unsigned int)hbv[rt][r];
        unsigned int p1 = (unsigned int)__shfl_xor((int)my16, 1);
        unsigned int u32v = (jloc & 1) ? ((my16 << 16) | p1) : ((p1 << 16) | my16);
        unsigned int u32o = (unsigned int)__shfl_xor((int)u32v, 2);
        unsigned long long u64v = (jloc & 2)
            ? (((unsigned long long)u32v << 32) | u32o)
            : (((unsigned long long)u32o << 32) | u32v);
        if ((jloc & 3) == 0) {
          int row = wave * 32 + rt * 16 + qq * 4 + r;
          __hip_atomic_store(&h2n[(size_t)row * 128 + ((hcol0 + jloc) >> 2)], u64v,
                             __ATOMIC_RELAXED, __HIP_MEMORY_SCOPE_AGENT);
        }
      }
    }

    // ---- signal: sc1 stores drained by syncthreads (vmcnt(0) before s_barrier) ----
    __syncthreads();
    if (tid == 0)
      __hip_atomic_fetch_add(myctr, 1u, __ATOMIC_RELAXED, __HIP_MEMORY_SCOPE_AGENT);

    // ---- non-critical tail: hs / final-state stores (plain, kernel-boundary vis) ----
    unsigned short* hst = hs + (size_t)t * (128 * 1024) + (dir << 9);
    #pragma unroll
    for (int rt = 0; rt < 2; rt++) {
      #pragma unroll
      for (int r = 0; r < 4; r++) {
        int row = wave * 32 + rt * 16 + qq * 4 + r;
        hst[(size_t)row * 1024 + hcol0 + jloc] = hbv[rt][r];
        if (s == 255) {
          size_t base = (size_t)SEQ * BATCH * OUTD + (size_t)dir * (BATCH * HID)
                      + (size_t)row * HID + hcol0 + jloc;
          dout[base] = hv[rt][r];                      // hN
          dout[base + 2 * (BATCH * HID)] = cv[rt][r];  // cN
        }
      }
    }

    // ---- overlap: x-part of step s+1 while others finish step s ----
    #pragma unroll
    for (int i = 0; i < 2; i++)
      #pragma unroll
      for (int j = 0; j < 4; j++) { f32x4 z = {0.f,0.f,0.f,0.f}; acc[i][j] = z; }
    if (s < 255) xpart(s + 1);
  }
}

// ---------------- launcher ----------------
extern "C" void kernel_launch(void* const* d_in, const int* in_sizes, int n_in,
                              void* d_out, int out_size, void* d_ws, size_t ws_size,
                              hipStream_t stream)
{
  const float* x      = (const float*)d_in[0];
  const float* wx_fwd = (const float*)d_in[1];
  const float* bx_fwd = (const float*)d_in[2];
  const float* wh_fwd = (const float*)d_in[3];
  const float* bh_fwd = (const float*)d_in[4];
  const float* wx_bwd = (const float*)d_in[5];
  const float* bx_bwd = (const float*)d_in[6];
  const float* wh_bwd = (const float*)d_in[7];
  const float* bh_bwd = (const float*)d_in[8];
  const float* wfc    = (const float*)d_in[9];
  const float* bfc    = (const float*)d_in[10];
  float* out = (float*)d_out;

  // ws layout (bytes); total ~85.5 MB (ws_size observed ~260 MB)
  const size_t WS_NEED = 85463040ULL;
  char* ws = (char*)d_ws;
  unsigned short* xbf  = (unsigned short*)(ws + 0);           // 16 MB  [32768][256] bf16
  unsigned short* wfcT = (unsigned short*)(ws + 16777216);    // 1 MB   [512][1024] bf16
  unsigned short* hs   = (unsigned short*)(ws + 17825792);    // 64 MB  [256][128][1024] bf16
  unsigned short* hbuf = (unsigned short*)(ws + 84934656);    // 512 KB [2][2][128][512] bf16
  uint32_t* ctr        = (uint32_t*)(ws + 85458944);          // 512 B  [2*64]

  (void)in_sizes; (void)n_in; (void)out_size;

  if (ws_size < WS_NEED) {
    k_diag<<<1, 64, 0, stream>>>(out, (float)(ws_size >> 20));
    return;
  }

  hipFuncSetAttribute((const void*)k_lstm, hipFuncAttributeMaxDynamicSharedMemorySize, 98304);

  // prep
  k_cast_bf16<<<8192, 256, 0, stream>>>(x, xbf, 2097152);
  k_transpose_cast<<<dim3(16, 32), 256, 0, stream>>>(wfc, wfcT, 1024, 512);
  k_zero<<<513, 256, 0, stream>>>((uint32_t*)hbuf, 131200);   // hbuf + ctr

  // recurrence (flush-free flag sync; 64 blocks on 256 CUs => co-resident)
  k_lstm<<<64, 256, 98304, stream>>>(wh_fwd, wh_bwd, wx_fwd, wx_bwd,
                                     bh_fwd, bh_bwd, bx_fwd, bx_bwd,
                                     xbf, hbuf, hs, out, ctr);

  // outputs = [hs_f | hs_b] @ wfc + bfc  (fp32 out)
  k_gemm<true><<<dim3(4, 256), 256, 0, stream>>>(
      hs, wfcT, wfcT, bfc, bfc, (void*)out, (void*)out, OUTD, 2 * HID, 4);
}

// Round 7
// 2480.510 us; speedup vs baseline: 1.8666x; 1.3130x over previous
//
#include <hip/hip_runtime.h>
#include <hip/hip_bf16.h>
#include <stdint.h>

// Problem dims
#define SEQ   256
#define BATCH 128
#define INPD  256
#define HID   512
#define OUTD  512
#define G4    2048   // 4*HID

typedef __attribute__((ext_vector_type(8))) short short8;
typedef __attribute__((ext_vector_type(4))) float f32x4;

typedef __attribute__((address_space(1))) void gv_t;
typedef __attribute__((address_space(3))) void lv_t;

__device__ inline unsigned short f2b(float f) {
  union { float f; uint32_t u; } v; v.f = f;
  uint32_t r = v.u + 0x7fffu + ((v.u >> 16) & 1u);   // RNE
  return (unsigned short)(r >> 16);
}
__device__ inline float b2f(unsigned short b) {
  union { uint32_t u; float f; } v; v.u = ((uint32_t)b) << 16; return v.f;
}
__device__ inline float fsig(float x) { return 1.f / (1.f + __expf(-x)); }
__device__ inline float ftanh(float x) {
  float a = fabsf(x);
  float u = __expf(-2.f * a);
  float t = (1.f - u) / (1.f + u);
  return copysignf(t, x);
}
__device__ inline f32x4 mfma16(short8 a, short8 b, f32x4 c) {
  return __builtin_amdgcn_mfma_f32_16x16x32_bf16(a, b, c, 0, 0, 0);
}
__device__ inline void llds16(const void* g, void* l) {
  __builtin_amdgcn_global_load_lds((gv_t*)g, (lv_t*)l, 16, 0, 0);
}

// device-scope (sc1) 16B load, counted-vmcnt (NOT compiler-serialized like atomics)
#define LDH(dst, base, OFF) \
  asm volatile("global_load_dwordx4 %0, %1, off offset:" #OFF " sc1" \
               : "=v"(dst) : "v"(base))
// counted wait + rule-18 fence
#define WAITV(N) do { \
  asm volatile("s_waitcnt vmcnt(" #N ")" ::: "memory"); \
  __builtin_amdgcn_sched_barrier(0); } while (0)

// ---------------- prep kernels ----------------

__global__ __launch_bounds__(256) void k_cast_bf16(const float* __restrict__ in,
                                                   unsigned short* __restrict__ out, int n4) {
  int i = blockIdx.x * 256 + threadIdx.x;
  if (i >= n4) return;
  float4 v = ((const float4*)in)[i];
  ushort4 o;
  o.x = f2b(v.x); o.y = f2b(v.y); o.z = f2b(v.z); o.w = f2b(v.w);
  ((ushort4*)out)[i] = o;
}

// out[n][k] = (bf16) in[k][n]   (in: [K][N] fp32)
__global__ __launch_bounds__(256) void k_transpose_cast(const float* __restrict__ in,
                                                        unsigned short* __restrict__ out,
                                                        int K, int N) {
  __shared__ float tile[32][33];
  int n0 = blockIdx.x * 32, k0 = blockIdx.y * 32;
  int tx = threadIdx.x & 31, ty = threadIdx.x >> 5;   // ty 0..7
  for (int r = ty; r < 32; r += 8) tile[r][tx] = in[(size_t)(k0 + r) * N + n0 + tx];
  __syncthreads();
  for (int r = ty; r < 32; r += 8) out[(size_t)(n0 + r) * K + k0 + tx] = f2b(tile[tx][r]);
}

__global__ __launch_bounds__(256) void k_zero(uint32_t* __restrict__ p, int n) {
  int i = blockIdx.x * 256 + threadIdx.x;
  if (i < n) p[i] = 0;
}

__global__ void k_diag(float* __restrict__ out, float v) {
  if (threadIdx.x == 0 && blockIdx.x == 0) out[0] = v;
}

// ---------------- bf16 GEMM:  C[m][n] = A[m][:]·Bt[n][:] + bias[n] ----------------
template<bool F32OUT>
__global__ __launch_bounds__(256) void k_gemm(
    const unsigned short* __restrict__ A,
    const unsigned short* __restrict__ Bt0, const unsigned short* __restrict__ Bt1,
    const float* __restrict__ bias0, const float* __restrict__ bias1,
    void* __restrict__ C0, void* __restrict__ C1,
    int ldc, int K, int ntilesPerDir)
{
  __shared__ unsigned short lds[2][2][8192];   // [buf][A/B][128 rows * 64 k] = 64 KB
  int bx = blockIdx.x;
  int dir = bx / ntilesPerDir;
  int ntile = bx - dir * ntilesPerDir;
  int mtile = blockIdx.y;
  const unsigned short* Bt = dir ? Bt1 : Bt0;
  const float* bias = dir ? bias1 : bias0;
  int m0 = mtile * 128, n0 = ntile * 128;
  int tid = threadIdx.x;
  int wave = tid >> 6, lane = tid & 63;
  int wr = wave >> 1, wc = wave & 1;
  int nkt = K >> 6;

  auto stage = [&](int buf, int kt) {
    #pragma unroll
    for (int half = 0; half < 2; half++) {
      const unsigned short* src = half ? Bt : A;
      int rowbase = half ? n0 : m0;
      #pragma unroll
      for (int i = 0; i < 4; i++) {
        int o = (i * 4 + wave) * 1024 + lane * 16;       // byte offset in 16KB tile
        int row = o >> 7;
        int kb  = o & 127;
        int kbs = kb ^ ((row & 7) << 4);                 // inverse-swizzled global source
        const char* ga = (const char*)src + (((size_t)(rowbase + row) * K + kt * 64) << 1) + kbs;
        char* lb = (char*)(&lds[buf][half][0]) + (i * 4 + wave) * 1024;  // wave-uniform base
        llds16(ga, lb);
      }
    }
  };

  f32x4 acc[4][4];
  #pragma unroll
  for (int i = 0; i < 4; i++)
    #pragma unroll
    for (int j = 0; j < 4; j++) { f32x4 z = {0.f,0.f,0.f,0.f}; acc[i][j] = z; }

  stage(0, 0);
  __syncthreads();
  for (int kt = 0; kt < nkt; kt++) {
    int buf = kt & 1;
    if (kt + 1 < nkt) stage(buf ^ 1, kt + 1);
    #pragma unroll
    for (int ks = 0; ks < 2; ks++) {
      short8 a[4], b[4];
      int kb = ks * 64 + ((lane >> 4) << 4);
      #pragma unroll
      for (int rt = 0; rt < 4; rt++) {
        int row = wr * 64 + rt * 16 + (lane & 15);
        int addr = row * 128 + (kb ^ ((row & 7) << 4));
        a[rt] = *(const short8*)((const char*)&lds[buf][0][0] + addr);
      }
      #pragma unroll
      for (int ct = 0; ct < 4; ct++) {
        int row = wc * 64 + ct * 16 + (lane & 15);
        int addr = row * 128 + (kb ^ ((row & 7) << 4));
        b[ct] = *(const short8*)((const char*)&lds[buf][1][0] + addr);
      }
      #pragma unroll
      for (int rt = 0; rt < 4; rt++)
        #pragma unroll
        for (int ct = 0; ct < 4; ct++)
          acc[rt][ct] = mfma16(a[rt], b[ct], acc[rt][ct]);
    }
    __syncthreads();
  }

  char* C = (char*)(dir ? C1 : C0);
  #pragma unroll
  for (int rt = 0; rt < 4; rt++) {
    #pragma unroll
    for (int ct = 0; ct < 4; ct++) {
      int coll = wc * 64 + ct * 16 + (lane & 15);
      float bv = bias[n0 + coll];
      #pragma unroll
      for (int r = 0; r < 4; r++) {
        int rowl = wr * 64 + rt * 16 + ((lane >> 4) << 2) + r;
        size_t off = (size_t)(m0 + rowl) * ldc + (n0 + coll);
        float v = acc[rt][ct][r] + bv;
        if (F32OUT) ((float*)C)[off] = v;
        else        ((unsigned short*)C)[off] = f2b(v);
      }
    }
  }
}

// ---------------- persistent bidirectional LSTM recurrence ----------------
// 64 WGs x 256 thr. WG (dir, cc) owns h-cols [16cc,16cc+16) => 64 gate-cols;
// [wh; wx] slice (K=768) LDS-resident (bf16, XOR-swizzled, 96KB dynamic; read-only
// after init => NO consumer-side __syncthreads in the loop).
// h exchange: inline-asm sc1 (device-scope) loads/stores with COUNTED vmcnt —
// round-6 lesson: __hip_atomic_load is compiler-serialized (vmcnt(0) per load,
// VGPR=88 signature); 32 batched 16B sc1 loads + vmcnt(28..0) blocks instead.
// Flags: per-direction relaxed agent monotonic counter, all-lane poll.
__global__ __launch_bounds__(256, 1) void k_lstm(
    const float* __restrict__ whf, const float* __restrict__ whb,
    const float* __restrict__ wxf, const float* __restrict__ wxb,
    const float* __restrict__ bhf, const float* __restrict__ bhb,
    const float* __restrict__ bxf, const float* __restrict__ bxb,
    const unsigned short* __restrict__ xbf,  // [256*128][256] bf16
    unsigned short* __restrict__ hbuf,       // [2][2][128][512] bf16 (zeroed)
    unsigned short* __restrict__ hs,         // [256][128][1024] bf16
    float* __restrict__ dout,
    uint32_t* __restrict__ ctr)              // [2*64] zeroed; ctr[dir*64]
{
  extern __shared__ char smem[];             // 96KB: [lg 0..63][k 0..767] bf16 swizzled
  int wg = blockIdx.x;
  int dir = wg >> 5;
  int cc = wg & 31;
  int hcol0 = cc << 4;
  const float* wh = dir ? whb : whf;
  const float* wx = dir ? wxb : wxf;
  const float* bh = dir ? bhb : bhf;
  const float* bx = dir ? bxb : bxf;
  int tid = threadIdx.x;
  int lane = tid & 63;
  int wave = tid >> 6;
  int jloc = lane & 15;
  int qq = lane >> 4;
  uint32_t* myctr = ctr + dir * 64;

  // stage [wh; wx] slice: lg -> gate (lg>>4), col hcol0+(lg&15); k<512: wh else wx
  for (int i = tid; i < 64 * 768; i += 256) {
    int lg = i & 63, k = i >> 6;
    int gcol = ((lg >> 4) << 9) + hcol0 + (lg & 15);
    float v = (k < 512) ? wh[(size_t)k * G4 + gcol]
                        : wx[(size_t)(k - 512) * G4 + gcol];
    int byteoff = lg * 1536 + ((k << 1) ^ ((lg & 7) << 4));
    *(unsigned short*)(smem + byteoff) = f2b(v);
  }
  float bh_r[4];
  #pragma unroll
  for (int g = 0; g < 4; g++)
    bh_r[g] = bh[(g << 9) + hcol0 + jloc] + bx[(g << 9) + hcol0 + jloc];
  float cr[8];
  #pragma unroll
  for (int r = 0; r < 8; r++) cr[r] = 0.f;
  __syncthreads();

  // acc[rt][ct][r] => preact(row = 32*wave+16*rt+4*qq+r, gate ct, col hcol0+jloc)
  f32x4 acc[2][4];
  #pragma unroll
  for (int i = 0; i < 2; i++)
    #pragma unroll
    for (int j = 0; j < 4; j++) { f32x4 z = {0.f,0.f,0.f,0.f}; acc[i][j] = z; }

  auto xpart = [&](int sn) {   // accumulate x_t @ wx into acc (k 512..767), plain loads
    int tn = dir ? (255 - sn) : sn;
    const unsigned short* xt = xbf + (size_t)tn * (128 * 256);
    #pragma unroll 2
    for (int ks = 16; ks < 24; ks++) {
      int kidx = ks * 32 + qq * 8;
      short8 b[4];
      #pragma unroll
      for (int ct = 0; ct < 4; ct++) {
        int lg = ct * 16 + jloc;
        b[ct] = *(const short8*)(smem + lg * 1536 + ((kidx << 1) ^ ((lg & 7) << 4)));
      }
      #pragma unroll
      for (int rt = 0; rt < 2; rt++) {
        int row = wave * 32 + rt * 16 + jloc;
        short8 a = *(const short8*)(xt + (size_t)row * 256 + (kidx - 512));
        #pragma unroll
        for (int ct = 0; ct < 4; ct++)
          acc[rt][ct] = mfma16(a, b[ct], acc[rt][ct]);
      }
    }
  };

  xpart(0);   // prologue

  for (int s = 0; s < 256; s++) {
    int t = dir ? (255 - s) : s;

    // ---- all-lane wait for h_s (32 WGs of this dir done with step s-1) ----
    if (s > 0) {
      uint32_t target = 32u * (uint32_t)s;
      while (__hip_atomic_load(myctr, __ATOMIC_RELAXED, __HIP_MEMORY_SCOPE_AGENT) < target)
        __builtin_amdgcn_s_sleep(1);
    }
    WAITV(0);   // drain stray xpart/hs ops -> counted scheme below is exact

    // ---- h-part MFMA (k 0..511): 32 batched sc1 16B loads, counted vmcnt ----
    const char* hpv = (const char*)(hbuf + ((size_t)(dir * 2 + (s & 1))) * (128 * 512));
    const char* ab0 = hpv + (((size_t)(wave * 32 + jloc) * 512 + qq * 8) << 1);
    const char* ab1 = ab0 + (16 * 512 * 2);
    short8 av[32];
    LDH(av[ 0], ab0,   0); LDH(av[ 1], ab0,  64); LDH(av[ 2], ab0, 128); LDH(av[ 3], ab0, 192);
    LDH(av[ 4], ab0, 256); LDH(av[ 5], ab0, 320); LDH(av[ 6], ab0, 384); LDH(av[ 7], ab0, 448);
    LDH(av[ 8], ab0, 512); LDH(av[ 9], ab0, 576); LDH(av[10], ab0, 640); LDH(av[11], ab0, 704);
    LDH(av[12], ab0, 768); LDH(av[13], ab0, 832); LDH(av[14], ab0, 896); LDH(av[15], ab0, 960);
    LDH(av[16], ab1,   0); LDH(av[17], ab1,  64); LDH(av[18], ab1, 128); LDH(av[19], ab1, 192);
    LDH(av[20], ab1, 256); LDH(av[21], ab1, 320); LDH(av[22], ab1, 384); LDH(av[23], ab1, 448);
    LDH(av[24], ab1, 512); LDH(av[25], ab1, 576); LDH(av[26], ab1, 640); LDH(av[27], ab1, 704);
    LDH(av[28], ab1, 768); LDH(av[29], ab1, 832); LDH(av[30], ab1, 896); LDH(av[31], ab1, 960);

#define HBLK(RT, KSB, VN) { \
    short8 bb[4][4]; \
    _Pragma("unroll") \
    for (int kq = 0; kq < 4; kq++) { \
      int kidx = (KSB + kq) * 32 + qq * 8; \
      _Pragma("unroll") \
      for (int ct = 0; ct < 4; ct++) { \
        int lg = ct * 16 + jloc; \
        bb[kq][ct] = *(const short8*)(smem + lg * 1536 + ((kidx << 1) ^ ((lg & 7) << 4))); \
      } \
    } \
    WAITV(VN); \
    _Pragma("unroll") \
    for (int kq = 0; kq < 4; kq++) \
      _Pragma("unroll") \
      for (int ct = 0; ct < 4; ct++) \
        acc[RT][ct] = mfma16(av[(RT) * 16 + KSB + kq], bb[kq][ct], acc[RT][ct]); \
  }
    HBLK(0,  0, 28); HBLK(0,  4, 24); HBLK(0,  8, 20); HBLK(0, 12, 16);
    HBLK(1,  0, 12); HBLK(1,  4,  8); HBLK(1,  8,  4); HBLK(1, 12,  0);
#undef HBLK

    // ---- in-register gate update; pack 4 cols -> u64; asm sc1 stores ----
    unsigned long long* h2n = (unsigned long long*)
        (hbuf + ((size_t)(dir * 2 + ((s + 1) & 1))) * (128 * 512));
    float hv[2][4], cv[2][4];
    unsigned long long pk[2][4];
    #pragma unroll
    for (int rt = 0; rt < 2; rt++) {
      #pragma unroll
      for (int r = 0; r < 4; r++) {
        int ci = rt * 4 + r;
        float gi = acc[rt][0][r] + bh_r[0];
        float gf = acc[rt][1][r] + bh_r[1];
        float go = acc[rt][2][r] + bh_r[2];
        float gc = acc[rt][3][r] + bh_r[3];
        float I = fsig(gi), F = fsig(gf), O = fsig(go), Ct = ftanh(gc);
        float cn = F * cr[ci] + I * Ct;
        cr[ci] = cn;
        float h = O * ftanh(cn);
        hv[rt][r] = h; cv[rt][r] = cn;
        // lane-quad pack: cols (hcol0 + (jloc&~3)) + 0..3 into one u64
        unsigned int my16 = (unsigned int)f2b(h);
        unsigned int p1 = (unsigned int)__shfl_xor((int)my16, 1);
        unsigned int u32v = (jloc & 1) ? ((my16 << 16) | p1) : ((p1 << 16) | my16);
        unsigned int u32o = (unsigned int)__shfl_xor((int)u32v, 2);
        pk[rt][r] = (jloc & 2)
            ? (((unsigned long long)u32v << 32) | u32o)
            : (((unsigned long long)u32o << 32) | u32v);
        if ((jloc & 3) == 0) {
          int row = wave * 32 + rt * 16 + qq * 4 + r;
          const unsigned long long* p = &h2n[(size_t)row * 128 + ((hcol0 + jloc) >> 2)];
          asm volatile("global_store_dwordx2 %0, %1, off sc1"
                       :: "v"(p), "v"(pk[rt][r]) : "memory");
        }
      }
    }

    // ---- drain sc1 stores, then signal ----
    WAITV(0);
    __syncthreads();
    if (tid == 0)
      __hip_atomic_fetch_add(myctr, 1u, __ATOMIC_RELAXED, __HIP_MEMORY_SCOPE_AGENT);

    // ---- non-critical tail: hs (packed u64) / final states ----
    unsigned short* hst = hs + (size_t)t * (128 * 1024) + (dir << 9);
    #pragma unroll
    for (int rt = 0; rt < 2; rt++) {
      #pragma unroll
      for (int r = 0; r < 4; r++) {
        int row = wave * 32 + rt * 16 + qq * 4 + r;
        if ((jloc & 3) == 0)
          *(unsigned long long*)(hst + (size_t)row * 1024 + hcol0 + jloc) = pk[rt][r];
        if (s == 255) {
          size_t base = (size_t)SEQ * BATCH * OUTD + (size_t)dir * (BATCH * HID)
                      + (size_t)row * HID + hcol0 + jloc;
          dout[base] = hv[rt][r];                      // hN
          dout[base + 2 * (BATCH * HID)] = cv[rt][r];  // cN
        }
      }
    }

    // ---- overlap: x-part of step s+1 while others finish step s ----
    #pragma unroll
    for (int i = 0; i < 2; i++)
      #pragma unroll
      for (int j = 0; j < 4; j++) { f32x4 z = {0.f,0.f,0.f,0.f}; acc[i][j] = z; }
    if (s < 255) xpart(s + 1);
  }
}

// ---------------- launcher ----------------
extern "C" void kernel_launch(void* const* d_in, const int* in_sizes, int n_in,
                              void* d_out, int out_size, void* d_ws, size_t ws_size,
                              hipStream_t stream)
{
  const float* x      = (const float*)d_in[0];
  const float* wx_fwd = (const float*)d_in[1];
  const float* bx_fwd = (const float*)d_in[2];
  const float* wh_fwd = (const float*)d_in[3];
  const float* bh_fwd = (const float*)d_in[4];
  const float* wx_bwd = (const float*)d_in[5];
  const float* bx_bwd = (const float*)d_in[6];
  const float* wh_bwd = (const float*)d_in[7];
  const float* bh_bwd = (const float*)d_in[8];
  const float* wfc    = (const float*)d_in[9];
  const float* bfc    = (const float*)d_in[10];
  float* out = (float*)d_out;

  // ws layout (bytes); total ~85.5 MB (ws_size observed ~260 MB)
  const size_t WS_NEED = 85463040ULL;
  char* ws = (char*)d_ws;
  unsigned short* xbf  = (unsigned short*)(ws + 0);           // 16 MB  [32768][256] bf16
  unsigned short* wfcT = (unsigned short*)(ws + 16777216);    // 1 MB   [512][1024] bf16
  unsigned short* hs   = (unsigned short*)(ws + 17825792);    // 64 MB  [256][128][1024] bf16
  unsigned short* hbuf = (unsigned short*)(ws + 84934656);    // 512 KB [2][2][128][512] bf16
  uint32_t* ctr        = (uint32_t*)(ws + 85458944);          // 512 B  [2*64]

  (void)in_sizes; (void)n_in; (void)out_size;

  if (ws_size < WS_NEED) {
    k_diag<<<1, 64, 0, stream>>>(out, (float)(ws_size >> 20));
    return;
  }

  hipFuncSetAttribute((const void*)k_lstm, hipFuncAttributeMaxDynamicSharedMemorySize, 98304);

  // prep
  k_cast_bf16<<<8192, 256, 0, stream>>>(x, xbf, 2097152);
  k_transpose_cast<<<dim3(16, 32), 256, 0, stream>>>(wfc, wfcT, 1024, 512);
  k_zero<<<513, 256, 0, stream>>>((uint32_t*)hbuf, 131200);   // hbuf + ctr

  // recurrence (flush-free flag sync; 64 blocks on 256 CUs => co-resident)
  k_lstm<<<64, 256, 98304, stream>>>(wh_fwd, wh_bwd, wx_fwd, wx_bwd,
                                     bh_fwd, bh_bwd, bx_fwd, bx_bwd,
                                     xbf, hbuf, hs, out, ctr);

  // outputs = [hs_f | hs_b] @ wfc + bfc  (fp32 out)
  k_gemm<true><<<dim3(4, 256), 256, 0, stream>>>(
      hs, wfcT, wfcT, bfc, bfc, (void*)out, (void*)out, OUTD, 2 * HID, 4);
}